// Round 2
// baseline (952.703 us; speedup 1.0000x reference)
//
#include <hip/hip_runtime.h>
#include <hip/hip_bf16.h>
#include <math.h>

// VectorQuantizer: X[32768,256] f32, W[4096,256] f32
// out = [quantized_st (32768*256 f32), loss (1 f32)]
#define NTOK 32768
#define NCODE 4096
#define DIM 256
#define NBLK 32  // NCODE / 128 code-blocks

// ws layout (bytes). Total needed: 8,601,600 B (~8.2 MB).
#define OFF_SUMS 0u        // f32[36864]: x_sq[32768] then w_sq[4096]
#define OFF_PART 147456u   // float2[32768][32]: per-(token,nblk) (d2min, idx)
#define OFF_LPART 8536064u // double[8192]: per-block loss partials

__device__ __forceinline__ void gload16(const float* g, float* l) {
  // async global->LDS, 16B per lane; dest must be wave-uniform base + lane*16
  __builtin_amdgcn_global_load_lds(
      (const __attribute__((address_space(1))) void*)g,
      (__attribute__((address_space(3))) void*)l, 16, 0, 0);
}

// ---------------- prep: x_sq and w_sq ----------------
__global__ __launch_bounds__(256) void vq_prep(const float* __restrict__ X,
                                               const float* __restrict__ W,
                                               float* __restrict__ sums) {
  const int tid = threadIdx.x;
  const int wave = tid >> 6, lane = tid & 63;
  const int row = blockIdx.x * 4 + wave;  // 0..36863
  const float* src = (row < NTOK) ? (X + (size_t)row * DIM)
                                  : (W + (size_t)(row - NTOK) * DIM);
  float4 v = reinterpret_cast<const float4*>(src)[lane];
  float s = v.x * v.x + v.y * v.y + v.z * v.z + v.w * v.w;
#pragma unroll
  for (int m = 1; m < 64; m <<= 1) s += __shfl_xor(s, m, 64);
  if (lane == 0) sums[row] = s;
}

// ---------------- main: fused GEMM + per-tile argmin ----------------
// Grid: 8192 blocks = 256 M-blocks x 32 N-blocks. Block: 256 thr, 128x128 tile.
__global__ __launch_bounds__(256, 2) void vq_main(
    const float* __restrict__ X, const float* __restrict__ W,
    const float* __restrict__ sums, float2* __restrict__ part) {
  __shared__ float lds[2][2][128 * 32];  // [dbuf][A/B][128 rows x 32 k] = 64 KB
  const int tid = threadIdx.x;
  const int bid = blockIdx.x;
  const int nblk = bid & (NBLK - 1);
  const int mblk = bid >> 5;
  const int mbase = mblk * 128, nbase = nblk * 128;
  const int tx = tid & 15, ty = tid >> 4;  // 16x16 thread grid, 8x8 regs each

  float acc[8][8];
#pragma unroll
  for (int r = 0; r < 8; ++r)
#pragma unroll
    for (int c = 0; c < 8; ++c) acc[r][c] = 0.f;

  // Stage one K-slice (128 rows x 32 floats) of A and B.
  // LDS is linear (global_load_lds requirement); the 16B-chunk XOR swizzle is
  // applied on the GLOBAL source address and undone identically on the read
  // (both-sides-or-neither, rule #21). swz = (row>>3)&7 breaks the
  // row-stride-128B same-bank pattern on the read side.
  auto stage = [&](int buf, int kt) {
#pragma unroll
    for (int it = 0; it < 4; ++it) {
      int L16 = it * 256 + tid;                      // 16B chunk id 0..1023
      int row = L16 >> 3;                            // 8 chunks per row
      int sch = (L16 & 7) ^ ((row >> 3) & 7);        // swizzled source chunk
      gload16(X + (size_t)(mbase + row) * DIM + kt * 32 + sch * 4,
              &lds[buf][0][L16 * 4]);
    }
#pragma unroll
    for (int it = 0; it < 4; ++it) {
      int L16 = it * 256 + tid;
      int row = L16 >> 3;
      int sch = (L16 & 7) ^ ((row >> 3) & 7);
      gload16(W + (size_t)(nbase + row) * DIM + kt * 32 + sch * 4,
              &lds[buf][1][L16 * 4]);
    }
  };

  stage(0, 0);
  __syncthreads();
  for (int kt = 0; kt < 8; ++kt) {
    const int cur = kt & 1;
    if (kt < 7) stage(cur ^ 1, kt + 1);  // prefetch next K-slice (async)
    const float* Ab = lds[cur][0];
    const float* Bb = lds[cur][1];
#pragma unroll
    for (int k4 = 0; k4 < 8; ++k4) {
      float4 a[8], b[8];
#pragma unroll
      for (int r = 0; r < 8; ++r) {
        int row = ty * 8 + r;  // row>>3 == ty
        a[r] = *(const float4*)(Ab + row * 32 + ((k4 ^ (ty & 7)) << 2));
      }
#pragma unroll
      for (int c = 0; c < 8; ++c) {
        int col = tx * 8 + c;  // col>>3 == tx
        b[c] = *(const float4*)(Bb + col * 32 + ((k4 ^ (tx & 7)) << 2));
      }
#pragma unroll
      for (int r = 0; r < 8; ++r)
#pragma unroll
        for (int c = 0; c < 8; ++c) {
          acc[r][c] = fmaf(a[r].x, b[c].x, acc[r][c]);
          acc[r][c] = fmaf(a[r].y, b[c].y, acc[r][c]);
          acc[r][c] = fmaf(a[r].z, b[c].z, acc[r][c]);
          acc[r][c] = fmaf(a[r].w, b[c].w, acc[r][c]);
        }
    }
    __syncthreads();
  }

  // Epilogue: d2 = (x_sq - 2*dot) + w_sq, replicating reference rounding
  // (2*dot is exact, so fmaf(-2,dot,x_sq) == x_sq - (2*dot) bit-exactly).
  float xs[8], wq[8];
#pragma unroll
  for (int r = 0; r < 8; ++r) xs[r] = sums[mbase + ty * 8 + r];
#pragma unroll
  for (int c = 0; c < 8; ++c) wq[c] = sums[NTOK + nbase + tx * 8 + c];
#pragma unroll
  for (int r = 0; r < 8; ++r) {
    float bv = INFINITY;
    int bi = 0x7fffffff;
#pragma unroll
    for (int c = 0; c < 8; ++c) {
      float d2 = fmaf(-2.f, acc[r][c], xs[r]) + wq[c];
      int gi = nbase + tx * 8 + c;
      if (d2 < bv) { bv = d2; bi = gi; }  // '<' keeps lowest index on ties
    }
    // reduce across the 16 tx lanes holding this row's other columns
#pragma unroll
    for (int m = 1; m <= 8; m <<= 1) {
      float ov = __shfl_xor(bv, m, 64);
      int oi = __shfl_xor(bi, m, 64);
      if (ov < bv || (ov == bv && oi < bi)) { bv = ov; bi = oi; }
    }
    if (tx == 0)
      part[(size_t)(mbase + ty * 8 + r) * NBLK + nblk] =
          make_float2(bv, __int_as_float(bi));
  }
}

// ---------------- final: cross-block argmin + gather + loss partials ---------
__global__ __launch_bounds__(256) void vq_final(
    const float* __restrict__ X, const float* __restrict__ W,
    const float2* __restrict__ part, float* __restrict__ out,
    double* __restrict__ lpart) {
  const int tid = threadIdx.x;
  const int wave = tid >> 6, lane = tid & 63;
  const int t = blockIdx.x * 4 + wave;  // token
  float bv = INFINITY;
  int bi = 0x7fffffff;
  if (lane < NBLK) {
    float2 c = part[(size_t)t * NBLK + lane];
    bv = c.x;
    bi = __float_as_int(c.y);
  }
#pragma unroll
  for (int m = 1; m <= 16; m <<= 1) {  // stays within 32-lane halves
    float ov = __shfl_xor(bv, m, 64);
    int oi = __shfl_xor(bi, m, 64);
    if (ov < bv || (ov == bv && oi < bi)) { bv = ov; bi = oi; }
  }
  bi = __shfl(bi, 0, 64);  // broadcast winner to all 64 lanes

  float4 xv = ((const float4*)(X + (size_t)t * DIM))[lane];
  float4 qv = ((const float4*)(W + (size_t)bi * DIM))[lane];
  float dx = qv.x - xv.x, dy = qv.y - xv.y, dz = qv.z - xv.z, dw = qv.w - xv.w;
  float4 o;  // quantized_st = x + (q - x), same two f32 roundings as reference
  o.x = xv.x + dx; o.y = xv.y + dy; o.z = xv.z + dz; o.w = xv.w + dw;
  ((float4*)(out + (size_t)t * DIM))[lane] = o;

  float ls = dx * dx + dy * dy + dz * dz + dw * dw;
#pragma unroll
  for (int m = 1; m < 64; m <<= 1) ls += __shfl_xor(ls, m, 64);
  __shared__ float wsum[4];
  if (lane == 0) wsum[wave] = ls;
  __syncthreads();
  if (tid == 0)
    lpart[blockIdx.x] =
        (double)wsum[0] + (double)wsum[1] + (double)wsum[2] + (double)wsum[3];
}

// ---------------- loss: deterministic single-block reduce ----------------
__global__ __launch_bounds__(256) void vq_loss(const double* __restrict__ lpart,
                                               float* __restrict__ out) {
  const int tid = threadIdx.x;
  double s = 0.0;
#pragma unroll
  for (int k = 0; k < 32; ++k) s += lpart[tid + 256 * k];
#pragma unroll
  for (int m = 1; m < 64; m <<= 1) s += __shfl_xor(s, m, 64);
  __shared__ double ws4[4];
  if ((tid & 63) == 0) ws4[tid >> 6] = s;
  __syncthreads();
  if (tid == 0)
    out[(size_t)NTOK * DIM] =
        (float)((ws4[0] + ws4[1] + ws4[2] + ws4[3]) * (1.25 / 8388608.0));
}

extern "C" void kernel_launch(void* const* d_in, const int* in_sizes, int n_in,
                              void* d_out, int out_size, void* d_ws,
                              size_t ws_size, hipStream_t stream) {
  const float* X = (const float*)d_in[0];   // inputs [32768,256]
  const float* W = (const float*)d_in[1];   // codebook [4096,256]
  float* out = (float*)d_out;               // 8388608 + 1 floats
  char* ws = (char*)d_ws;                   // needs ~8.2 MB
  float* sums = (float*)(ws + OFF_SUMS);
  float2* part = (float2*)(ws + OFF_PART);
  double* lpart = (double*)(ws + OFF_LPART);

  vq_prep<<<(NTOK + NCODE) / 4, 256, 0, stream>>>(X, W, sums);
  vq_main<<<(NTOK / 128) * NBLK, 256, 0, stream>>>(X, W, sums, part);
  vq_final<<<NTOK / 4, 256, 0, stream>>>(X, W, part, out, lpart);
  vq_loss<<<1, 256, 0, stream>>>(lpart, out);
}

// Round 5
// 714.618 us; speedup vs baseline: 1.3332x; 1.3332x over previous
//
#include <hip/hip_runtime.h>
#include <hip/hip_bf16.h>
#include <math.h>

// VectorQuantizer: X[32768,256] f32, W[4096,256] f32
// out = [quantized_st (32768*256 f32), loss (1 f32)]
// Pass 1: 3-term bf16-split MFMA GEMM -> per-(token,tile) min of f32-rounded d2'
// Pass 2: exact f32 recompute of candidate tiles (provably contains ref argmin)
#define NTOK 32768
#define NCODE 4096
#define DIM 256
#define NT 32  // code tiles of 128

typedef short bf16x8 __attribute__((ext_vector_type(8)));
typedef float f32x16 __attribute__((ext_vector_type(16)));

// ---- big-ws layout (bytes), total 46,612,736 ----
#define OFF_XH 0u
#define OFF_XL 16777216u
#define OFF_WH 33554432u
#define OFF_WL 35651584u
#define OFF_SUMS 37748736u   // f32[36864]
#define OFF_PART 37896192u   // f32[32768][32] tile-min of d2'
#define OFF_CNT 42090496u    // int[32] (+pad)
#define OFF_LIST 42090752u   // int[32][32768]
#define OFF_WIN 46285056u    // u64[32768]
#define OFF_LPART 46547200u  // double[8192]
#define WS_NEEDED 46612736ull
// ---- small-ws (fallback, validated round 2) ----
#define OFF_SUMS_O 0u
#define OFF_PART_O 147456u
#define OFF_LPART_O 8536064u

__device__ __forceinline__ void gload16(const void* g, void* l) {
  __builtin_amdgcn_global_load_lds(
      (const __attribute__((address_space(1))) void*)g,
      (__attribute__((address_space(3))) void*)l, 16, 0, 0);
}
__device__ __forceinline__ unsigned short bfh(float f) {
  __hip_bfloat16 h = __float2bfloat16(f);
  return *reinterpret_cast<unsigned short*>(&h);
}
__device__ __forceinline__ float bff(unsigned short u) {
  __hip_bfloat16 h = *reinterpret_cast<__hip_bfloat16*>(&u);
  return __bfloat162float(h);
}

// ---------------- prep: sums (+ bf16 hi/lo split, + zero cnt) ----------------
__global__ __launch_bounds__(256) void vq_prep(
    const float* __restrict__ X, const float* __restrict__ W,
    float* __restrict__ sums, unsigned short* __restrict__ xh,
    unsigned short* __restrict__ xl, unsigned short* __restrict__ wh,
    unsigned short* __restrict__ wl, int* __restrict__ cnt, int conv) {
  const int tid = threadIdx.x;
  if (conv && blockIdx.x == 0 && tid < NT) cnt[tid] = 0;
  const int wave = tid >> 6, lane = tid & 63;
  const int row = blockIdx.x * 4 + wave;  // 0..36863
  const bool isx = row < NTOK;
  const float* src = isx ? (X + (size_t)row * DIM)
                         : (W + (size_t)(row - NTOK) * DIM);
  float4 v = reinterpret_cast<const float4*>(src)[lane];
  float s = v.x * v.x + v.y * v.y + v.z * v.z + v.w * v.w;
#pragma unroll
  for (int m = 1; m < 64; m <<= 1) s += __shfl_xor(s, m, 64);
  if (lane == 0) sums[row] = s;
  if (conv) {
    unsigned short h0 = bfh(v.x), h1 = bfh(v.y), h2 = bfh(v.z), h3 = bfh(v.w);
    ushort4 hi = make_ushort4(h0, h1, h2, h3);
    ushort4 lo = make_ushort4(bfh(v.x - bff(h0)), bfh(v.y - bff(h1)),
                              bfh(v.z - bff(h2)), bfh(v.w - bff(h3)));
    const int r = isx ? row : row - NTOK;
    unsigned short* dh = isx ? xh : wh;
    unsigned short* dl = isx ? xl : wl;
    ((ushort4*)(dh + (size_t)r * DIM))[lane] = hi;
    ((ushort4*)(dl + (size_t)r * DIM))[lane] = lo;
  }
}

// ---------------- pass 1: 3-term bf16 MFMA GEMM + per-tile d2' min ----------
// Grid 8192 = 256 mblk x 32 nblk. 256 thr = 4 waves (2x2), wave tile 64x64.
// K=768 effective: [Xh|Xh|Xl] . [Wh|Wl|Wh], BK=64, double-buffered LDS.
__global__ __launch_bounds__(256, 2) void vq_mfma(
    const unsigned short* __restrict__ xh, const unsigned short* __restrict__ xl,
    const unsigned short* __restrict__ wh, const unsigned short* __restrict__ wl,
    const float* __restrict__ sums, float* __restrict__ part) {
  __shared__ short lds[2][2][8192];  // [dbuf][A/B][128 rows x 64 bf16] = 64 KB
  const int tid = threadIdx.x;
  const int wave = tid >> 6, lane = tid & 63;
  const int wr = wave >> 1, wc = wave & 1;
  const int half = lane >> 5, l31 = lane & 31;
  const int nblk = blockIdx.x & (NT - 1);
  const int mbase = (blockIdx.x >> 5) * 128, nbase = nblk * 128;

  f32x16 acc00, acc01, acc10, acc11;
#pragma unroll
  for (int i = 0; i < 16; ++i) {
    acc00[i] = 0.f; acc01[i] = 0.f; acc10[i] = 0.f; acc11[i] = 0.f;
  }

  // LDS[row][cc] = SRC[row][cc ^ (row&7)]  (both-sides XOR swizzle; LDS dest
  // linear per global_load_lds; source chunk pre-swizzled; read undoes it)
  auto stage = [&](int buf, int kt) {
    const int rgn = kt >> 2;  // 0:Xh.Wh 1:Xh.Wl 2:Xl.Wh
    const unsigned short* As = (rgn < 2) ? xh : xl;
    const unsigned short* Bs = (rgn == 0) ? wh : ((rgn == 1) ? wl : wh);
    const int k0 = (kt & 3) * 64;
#pragma unroll
    for (int it = 0; it < 4; ++it) {
      int L = it * 256 + tid;          // 16B-chunk id 0..1023 (8 chunks/row)
      int row = L >> 3, cc = L & 7;
      int off = k0 + ((cc ^ (row & 7)) << 3);
      gload16(As + (size_t)(mbase + row) * DIM + off, &lds[buf][0][L << 3]);
    }
#pragma unroll
    for (int it = 0; it < 4; ++it) {
      int L = it * 256 + tid;
      int row = L >> 3, cc = L & 7;
      int off = k0 + ((cc ^ (row & 7)) << 3);
      gload16(Bs + (size_t)(nbase + row) * DIM + off, &lds[buf][1][L << 3]);
    }
  };
  auto frag = [&](const short* b, int row, int kc) -> bf16x8 {
    return *(const bf16x8*)(b + row * 64 + ((kc ^ (row & 7)) << 3));
  };
  auto compute = [&](int buf) {
    const short* As = lds[buf][0];
    const short* Bs = lds[buf][1];
    const int r0 = wr * 64 + l31, r1 = r0 + 32;
    const int c0 = wc * 64 + l31, c1 = c0 + 32;
#pragma unroll
    for (int ks = 0; ks < 4; ++ks) {
      const int kc = ks * 2 + half;  // lane holds k = kc*8..kc*8+7
      bf16x8 a0 = frag(As, r0, kc), a1 = frag(As, r1, kc);
      bf16x8 b0 = frag(Bs, c0, kc), b1 = frag(Bs, c1, kc);
      acc00 = __builtin_amdgcn_mfma_f32_32x32x16_bf16(a0, b0, acc00, 0, 0, 0);
      acc01 = __builtin_amdgcn_mfma_f32_32x32x16_bf16(a0, b1, acc01, 0, 0, 0);
      acc10 = __builtin_amdgcn_mfma_f32_32x32x16_bf16(a1, b0, acc10, 0, 0, 0);
      acc11 = __builtin_amdgcn_mfma_f32_32x32x16_bf16(a1, b1, acc11, 0, 0, 0);
    }
  };

  stage(0, 0);
  __syncthreads();
  for (int kt = 0; kt < 12; ++kt) {
    const int cur = kt & 1;
    if (kt < 11) stage(cur ^ 1, kt + 1);
    compute(cur);
    __syncthreads();
  }

  // epilogue: d2' = fmaf(-2,acc,xs)+wq (same rounding as ref), per-row tile min
  float* redm = (float*)lds;  // [128][2], lds free after final barrier
  const float wq0 = sums[NTOK + nbase + wc * 64 + l31];
  const float wq1 = sums[NTOK + nbase + wc * 64 + l31 + 32];
  auto epi = [&](int mf, const f32x16& A0, const f32x16& A1) {
#pragma unroll
    for (int reg = 0; reg < 16; ++reg) {
      int rl = wr * 64 + mf * 32 + (reg & 3) + ((reg >> 2) << 3) + (half << 2);
      float xs = sums[mbase + rl];
      float d0 = fmaf(-2.f, A0[reg], xs) + wq0;
      float d1 = fmaf(-2.f, A1[reg], xs) + wq1;
      float v = fminf(d0, d1);
#pragma unroll
      for (int m = 1; m <= 16; m <<= 1) v = fminf(v, __shfl_xor(v, m, 64));
      if (l31 == 0) redm[rl * 2 + wc] = v;  // all lanes of half hold same v
    }
  };
  epi(0, acc00, acc01);
  epi(1, acc10, acc11);
  __syncthreads();
  if (tid < 128)
    part[(size_t)(mbase + tid) * NT + nblk] = fminf(redm[tid * 2], redm[tid * 2 + 1]);
}

// ------- candidate tiles: thr = gmin + 2.5e-4 (>= 2E, E<=6.2e-5, 2x margin) --
__global__ __launch_bounds__(256) void vq_cand(
    const float* __restrict__ part, int* __restrict__ cnt, int* __restrict__ list,
    unsigned long long* __restrict__ winner) {
  const int t = blockIdx.x * 256 + threadIdx.x;
  const int lane = threadIdx.x & 63;
  const float* p = part + (size_t)t * NT;
  float g = p[0];
#pragma unroll
  for (int i = 1; i < NT; ++i) g = fminf(g, p[i]);
  winner[t] = ~0ull;
  const float thr = g + 2.5e-4f;
#pragma unroll 1
  for (int tau = 0; tau < NT; ++tau) {
    bool take = p[tau] <= thr;
    unsigned long long mask = __ballot(take);
    if (mask) {
      int leader = __ffsll((unsigned long long)mask) - 1;
      int nw = __popcll(mask);
      int base = 0;
      if (lane == leader) base = atomicAdd(&cnt[tau], nw);
      base = __shfl(base, leader, 64);
      if (take) {
        int pre = __popcll(mask & ((1ull << lane) - 1));
        list[tau * NTOK + base + pre] = t;
      }
    }
  }
}

// ------- pass 2: exact f32 d2 on candidate tiles (validated core/rounding) --
__global__ __launch_bounds__(256, 2) void vq_exact(
    const float* __restrict__ X, const float* __restrict__ W,
    const float* __restrict__ sums, const int* __restrict__ cnt,
    const int* __restrict__ list, unsigned long long* __restrict__ winner) {
  __shared__ float lds[2][2][128 * 32];
  __shared__ int ids[128];
  const int tid = threadIdx.x;
  const int tau = blockIdx.x >> 3, slot = blockIdx.x & 7;
  const int tx = tid & 15, ty = tid >> 4;
  const int count = cnt[tau];
  const int nbase = tau * 128;
  float wq[8];
#pragma unroll
  for (int c = 0; c < 8; ++c) wq[c] = sums[NTOK + nbase + tx * 8 + c];

  for (int base = slot * 128; base < count; base += 1024) {
    __syncthreads();
    if (tid < 128) ids[tid] = list[tau * NTOK + min(base + tid, count - 1)];
    __syncthreads();
    int ar[4];
#pragma unroll
    for (int it = 0; it < 4; ++it) ar[it] = ids[(it * 256 + tid) >> 3];
    float acc[8][8];
#pragma unroll
    for (int r = 0; r < 8; ++r)
#pragma unroll
      for (int c = 0; c < 8; ++c) acc[r][c] = 0.f;
    auto stage = [&](int buf, int kt) {
#pragma unroll
      for (int it = 0; it < 4; ++it) {
        int L16 = it * 256 + tid;
        int row = L16 >> 3;
        int sch = (L16 & 7) ^ ((row >> 3) & 7);
        gload16(X + (size_t)ar[it] * DIM + kt * 32 + sch * 4, &lds[buf][0][L16 * 4]);
      }
#pragma unroll
      for (int it = 0; it < 4; ++it) {
        int L16 = it * 256 + tid;
        int row = L16 >> 3;
        int sch = (L16 & 7) ^ ((row >> 3) & 7);
        gload16(W + (size_t)(nbase + row) * DIM + kt * 32 + sch * 4,
                &lds[buf][1][L16 * 4]);
      }
    };
    stage(0, 0);
    __syncthreads();
    for (int kt = 0; kt < 8; ++kt) {
      const int cur = kt & 1;
      if (kt < 7) stage(cur ^ 1, kt + 1);
      const float* Ab = lds[cur][0];
      const float* Bb = lds[cur][1];
#pragma unroll
      for (int k4 = 0; k4 < 8; ++k4) {
        float4 a[8], b[8];
#pragma unroll
        for (int r = 0; r < 8; ++r)
          a[r] = *(const float4*)(Ab + (ty * 8 + r) * 32 + ((k4 ^ (ty & 7)) << 2));
#pragma unroll
        for (int c = 0; c < 8; ++c)
          b[c] = *(const float4*)(Bb + (tx * 8 + c) * 32 + ((k4 ^ (tx & 7)) << 2));
#pragma unroll
        for (int r = 0; r < 8; ++r)
#pragma unroll
          for (int c = 0; c < 8; ++c) {
            acc[r][c] = fmaf(a[r].x, b[c].x, acc[r][c]);
            acc[r][c] = fmaf(a[r].y, b[c].y, acc[r][c]);
            acc[r][c] = fmaf(a[r].z, b[c].z, acc[r][c]);
            acc[r][c] = fmaf(a[r].w, b[c].w, acc[r][c]);
          }
      }
      __syncthreads();
    }
#pragma unroll
    for (int r = 0; r < 8; ++r) {
      const int lrow = ty * 8 + r;
      const int id = ids[lrow];
      const float xs = sums[id];
      unsigned long long best = ~0ull;
#pragma unroll
      for (int c = 0; c < 8; ++c) {
        float d2 = fmaf(-2.f, acc[r][c], xs) + wq[c];  // == ref rounding
        unsigned long long pk =
            ((unsigned long long)__float_as_uint(d2) << 32) |
            (unsigned)(nbase + tx * 8 + c);
        best = best < pk ? best : pk;
      }
#pragma unroll
      for (int m = 1; m <= 8; m <<= 1) {
        unsigned long long o = __shfl_xor(best, m, 64);
        best = best < o ? best : o;
      }
      if (tx == 0 && base + lrow < count) atomicMin(&winner[id], best);
    }
  }
}

// ---------------- output + loss partials ----------------
__global__ __launch_bounds__(256) void vq_out(
    const float* __restrict__ X, const float* __restrict__ W,
    const unsigned long long* __restrict__ winner, float* __restrict__ out,
    double* __restrict__ lpart) {
  const int tid = threadIdx.x;
  const int wave = tid >> 6, lane = tid & 63;
  const int t = blockIdx.x * 4 + wave;
  const unsigned idx = (unsigned)(winner[t] & 0xFFFFFFFFull);
  float4 xv = ((const float4*)(X + (size_t)t * DIM))[lane];
  float4 qv = ((const float4*)(W + (size_t)idx * DIM))[lane];
  float dx = qv.x - xv.x, dy = qv.y - xv.y, dz = qv.z - xv.z, dw = qv.w - xv.w;
  float4 o;
  o.x = xv.x + dx; o.y = xv.y + dy; o.z = xv.z + dz; o.w = xv.w + dw;
  ((float4*)(out + (size_t)t * DIM))[lane] = o;
  float ls = dx * dx + dy * dy + dz * dz + dw * dw;
#pragma unroll
  for (int m = 1; m < 64; m <<= 1) ls += __shfl_xor(ls, m, 64);
  __shared__ float wsum[4];
  if (lane == 0) wsum[wave] = ls;
  __syncthreads();
  if (tid == 0)
    lpart[blockIdx.x] =
        (double)wsum[0] + (double)wsum[1] + (double)wsum[2] + (double)wsum[3];
}

__global__ __launch_bounds__(256) void vq_loss(const double* __restrict__ lpart,
                                               float* __restrict__ out) {
  const int tid = threadIdx.x;
  double s = 0.0;
#pragma unroll
  for (int k = 0; k < 32; ++k) s += lpart[tid + 256 * k];
#pragma unroll
  for (int m = 1; m < 64; m <<= 1) s += __shfl_xor(s, m, 64);
  __shared__ double ws4[4];
  if ((tid & 63) == 0) ws4[tid >> 6] = s;
  __syncthreads();
  if (tid == 0)
    out[(size_t)NTOK * DIM] =
        (float)((ws4[0] + ws4[1] + ws4[2] + ws4[3]) * (1.25 / 8388608.0));
}

// ============ fallback path (round-2 validated f32 kernels) ============
__global__ __launch_bounds__(256, 2) void vq_main_f32(
    const float* __restrict__ X, const float* __restrict__ W,
    const float* __restrict__ sums, float2* __restrict__ part) {
  __shared__ float lds[2][2][128 * 32];
  const int tid = threadIdx.x;
  const int nblk = blockIdx.x & (NT - 1);
  const int mbase = (blockIdx.x >> 5) * 128, nbase = nblk * 128;
  const int tx = tid & 15, ty = tid >> 4;
  float acc[8][8];
#pragma unroll
  for (int r = 0; r < 8; ++r)
#pragma unroll
    for (int c = 0; c < 8; ++c) acc[r][c] = 0.f;
  auto stage = [&](int buf, int kt) {
#pragma unroll
    for (int it = 0; it < 4; ++it) {
      int L16 = it * 256 + tid;
      int row = L16 >> 3;
      int sch = (L16 & 7) ^ ((row >> 3) & 7);
      gload16(X + (size_t)(mbase + row) * DIM + kt * 32 + sch * 4,
              &lds[buf][0][L16 * 4]);
    }
#pragma unroll
    for (int it = 0; it < 4; ++it) {
      int L16 = it * 256 + tid;
      int row = L16 >> 3;
      int sch = (L16 & 7) ^ ((row >> 3) & 7);
      gload16(W + (size_t)(nbase + row) * DIM + kt * 32 + sch * 4,
              &lds[buf][1][L16 * 4]);
    }
  };
  stage(0, 0);
  __syncthreads();
  for (int kt = 0; kt < 8; ++kt) {
    const int cur = kt & 1;
    if (kt < 7) stage(cur ^ 1, kt + 1);
    const float* Ab = lds[cur][0];
    const float* Bb = lds[cur][1];
#pragma unroll
    for (int k4 = 0; k4 < 8; ++k4) {
      float4 a[8], b[8];
#pragma unroll
      for (int r = 0; r < 8; ++r)
        a[r] = *(const float4*)(Ab + (ty * 8 + r) * 32 + ((k4 ^ (ty & 7)) << 2));
#pragma unroll
      for (int c = 0; c < 8; ++c)
        b[c] = *(const float4*)(Bb + (tx * 8 + c) * 32 + ((k4 ^ (tx & 7)) << 2));
#pragma unroll
      for (int r = 0; r < 8; ++r)
#pragma unroll
        for (int c = 0; c < 8; ++c) {
          acc[r][c] = fmaf(a[r].x, b[c].x, acc[r][c]);
          acc[r][c] = fmaf(a[r].y, b[c].y, acc[r][c]);
          acc[r][c] = fmaf(a[r].z, b[c].z, acc[r][c]);
          acc[r][c] = fmaf(a[r].w, b[c].w, acc[r][c]);
        }
    }
    __syncthreads();
  }
  float xs[8], wq[8];
#pragma unroll
  for (int r = 0; r < 8; ++r) xs[r] = sums[mbase + ty * 8 + r];
#pragma unroll
  for (int c = 0; c < 8; ++c) wq[c] = sums[NTOK + nbase + tx * 8 + c];
#pragma unroll
  for (int r = 0; r < 8; ++r) {
    float bv = INFINITY;
    int bi = 0x7fffffff;
#pragma unroll
    for (int c = 0; c < 8; ++c) {
      float d2 = fmaf(-2.f, acc[r][c], xs[r]) + wq[c];
      int gi = nbase + tx * 8 + c;
      if (d2 < bv) { bv = d2; bi = gi; }
    }
#pragma unroll
    for (int m = 1; m <= 8; m <<= 1) {
      float ov = __shfl_xor(bv, m, 64);
      int oi = __shfl_xor(bi, m, 64);
      if (ov < bv || (ov == bv && oi < bi)) { bv = ov; bi = oi; }
    }
    if (tx == 0)
      part[(size_t)(mbase + ty * 8 + r) * NT + nblk] =
          make_float2(bv, __int_as_float(bi));
  }
}

__global__ __launch_bounds__(256) void vq_final_f32(
    const float* __restrict__ X, const float* __restrict__ W,
    const float2* __restrict__ part, float* __restrict__ out,
    double* __restrict__ lpart) {
  const int tid = threadIdx.x;
  const int wave = tid >> 6, lane = tid & 63;
  const int t = blockIdx.x * 4 + wave;
  float bv = INFINITY;
  int bi = 0x7fffffff;
  if (lane < NT) {
    float2 c = part[(size_t)t * NT + lane];
    bv = c.x;
    bi = __float_as_int(c.y);
  }
#pragma unroll
  for (int m = 1; m <= 16; m <<= 1) {
    float ov = __shfl_xor(bv, m, 64);
    int oi = __shfl_xor(bi, m, 64);
    if (ov < bv || (ov == bv && oi < bi)) { bv = ov; bi = oi; }
  }
  bi = __shfl(bi, 0, 64);
  float4 xv = ((const float4*)(X + (size_t)t * DIM))[lane];
  float4 qv = ((const float4*)(W + (size_t)bi * DIM))[lane];
  float dx = qv.x - xv.x, dy = qv.y - xv.y, dz = qv.z - xv.z, dw = qv.w - xv.w;
  float4 o;
  o.x = xv.x + dx; o.y = xv.y + dy; o.z = xv.z + dz; o.w = xv.w + dw;
  ((float4*)(out + (size_t)t * DIM))[lane] = o;
  float ls = dx * dx + dy * dy + dz * dz + dw * dw;
#pragma unroll
  for (int m = 1; m < 64; m <<= 1) ls += __shfl_xor(ls, m, 64);
  __shared__ float wsum[4];
  if (lane == 0) wsum[wave] = ls;
  __syncthreads();
  if (tid == 0)
    lpart[blockIdx.x] =
        (double)wsum[0] + (double)wsum[1] + (double)wsum[2] + (double)wsum[3];
}

extern "C" void kernel_launch(void* const* d_in, const int* in_sizes, int n_in,
                              void* d_out, int out_size, void* d_ws,
                              size_t ws_size, hipStream_t stream) {
  const float* X = (const float*)d_in[0];
  const float* W = (const float*)d_in[1];
  float* out = (float*)d_out;
  char* ws = (char*)d_ws;
  if (ws_size >= WS_NEEDED) {
    unsigned short* xh = (unsigned short*)(ws + OFF_XH);
    unsigned short* xl = (unsigned short*)(ws + OFF_XL);
    unsigned short* wh = (unsigned short*)(ws + OFF_WH);
    unsigned short* wl = (unsigned short*)(ws + OFF_WL);
    float* sums = (float*)(ws + OFF_SUMS);
    float* part = (float*)(ws + OFF_PART);
    int* cnt = (int*)(ws + OFF_CNT);
    int* list = (int*)(ws + OFF_LIST);
    unsigned long long* win = (unsigned long long*)(ws + OFF_WIN);
    double* lpart = (double*)(ws + OFF_LPART);
    vq_prep<<<(NTOK + NCODE) / 4, 256, 0, stream>>>(X, W, sums, xh, xl, wh, wl,
                                                    cnt, 1);
    vq_mfma<<<(NTOK / 128) * NT, 256, 0, stream>>>(xh, xl, wh, wl, sums, part);
    vq_cand<<<NTOK / 256, 256, 0, stream>>>(part, cnt, list, win);
    vq_exact<<<NT * 8, 256, 0, stream>>>(X, W, sums, cnt, list, win);
    vq_out<<<NTOK / 4, 256, 0, stream>>>(X, W, win, out, lpart);
    vq_loss<<<1, 256, 0, stream>>>(lpart, out);
  } else {
    float* sums = (float*)(ws + OFF_SUMS_O);
    float2* part = (float2*)(ws + OFF_PART_O);
    double* lpart = (double*)(ws + OFF_LPART_O);
    vq_prep<<<(NTOK + NCODE) / 4, 256, 0, stream>>>(
        X, W, sums, nullptr, nullptr, nullptr, nullptr, nullptr, 0);
    vq_main_f32<<<(NTOK / 128) * NT, 256, 0, stream>>>(X, W, sums, part);
    vq_final_f32<<<NTOK / 4, 256, 0, stream>>>(X, W, part, out, lpart);
    vq_loss<<<1, 256, 0, stream>>>(lpart, out);
  }
}